// Round 21
// baseline (48.310 us; speedup 1.0000x reference)
//
#include <hip/hip_runtime.h>

#define NQ    14
#define NPAR  196
#define NCLS  10

// ============================================================================
// MPS/Heisenberg formulation — algebra verified on HW in r19/r20 (absmax 0).
// r21: identical arithmetic; the three transfer chains (L^I, L^Z top-down and
// P bottom-up) now run in ONE wave with interleaved issue (3x ILP per latency
// hop) and a fully unrolled site loop (compile-time At addresses -> load
// prefetch). Centers (42 tasks across 16 waves) unchanged from r20.
// ============================================================================

__device__ __forceinline__ float2 cmul(float2 a, float2 b) {
    return make_float2(a.x*b.x - a.y*b.y, a.x*b.y + a.y*b.x);
}
__device__ __forceinline__ float2 cmulc(float2 a, float2 b) {   // conj(a)*b
    return make_float2(a.x*b.x + a.y*b.y, a.x*b.y - a.y*b.x);
}
__device__ __forceinline__ float2 cadd(float2 a, float2 b) {
    return make_float2(a.x + b.x, a.y + b.y);
}
__device__ __forceinline__ float2 csub(float2 a, float2 b) {
    return make_float2(a.x - b.x, a.y - b.y);
}
__device__ __forceinline__ float2 shfl2(float2 v, int src) {
    return make_float2(__shfl(v.x, src, 64), __shfl(v.y, src, 64));
}

__global__ void __launch_bounds__(1024)
qvc_mps(const float* __restrict__ x, const float* __restrict__ Wm,
        const float* __restrict__ bias, float* __restrict__ out)
{
    __shared__ float  uc[70][8];
    __shared__ float2 At[14][2][64];   // site s, phys h, 8x8 [row*8+col]
    __shared__ float2 LI[15][64];      // L^I prefixes (LI[14] = base)
    __shared__ float2 LZ[15][64];      // L^Z prefixes
    __shared__ float2 Ps[14][64];      // Ps[t] = P after sites 0..t-1 (Ps[0]=ones)
    __shared__ float  abcd[NQ][4];
    __shared__ float  Tv2[NQ][3];      // Tz, Tx, Ty per q
    __shared__ float  Eq[NQ];

    const int e = blockIdx.x;
    const int tid = threadIdx.x;
    const int wave = tid >> 6, lane = tid & 63;
    const int i8 = lane >> 3, j8 = lane & 7;
    const float* xb = x + e * NPAR;

    // ---- all 70 gate 2x2s (verified) ----
    if (tid < 70) {
        const int layer = tid / 14, q = tid % 14;
        const int pidx = (layer < 4) ? layer * 42 + q * 3 : 168 + q * 2;
        float a1 = 0.5f * xb[pidx], a2 = 0.5f * xb[pidx + 1];
        float s1, c1, s2, c2;
        sincosf(a1, &s1, &c1);
        sincosf(a2, &s2, &c2);
        float A00r =  c2 * c1, A00i =  s2 * s1;
        float A01r = -s2 * c1, A01i = -c2 * s1;
        float A10r =  s2 * c1, A10i = -c2 * s1;
        float A11r =  c2 * c1, A11i = -s2 * s1;
        float U0, U1, U2, U3, U4, U5, U6, U7;
        if (layer < 4) {
            float a3 = 0.5f * xb[pidx + 2]; float s3, c3; sincosf(a3, &s3, &c3);
            U0 = c3 * A00r + s3 * A00i; U1 = c3 * A00i - s3 * A00r;
            U2 = c3 * A01r + s3 * A01i; U3 = c3 * A01i - s3 * A01r;
            U4 = c3 * A10r - s3 * A10i; U5 = c3 * A10i + s3 * A10r;
            U6 = c3 * A11r - s3 * A11i; U7 = c3 * A11i + s3 * A11r;
        } else {
            U0 = A00r; U1 = A00i; U2 = A01r; U3 = A01i;
            U4 = A10r; U5 = A10i; U6 = A11r; U7 = A11i;
        }
        uc[tid][0] = U0; uc[tid][1] = U1; uc[tid][2] = U2; uc[tid][3] = U3;
        uc[tid][4] = U4; uc[tid][5] = U5; uc[tid][6] = U6; uc[tid][7] = U7;
    }
    __syncthreads();

    // ---- Pauli coefficients of M_q = u4^dag Z u4 (verified r19) ----
    if (tid < NQ) {
        const float* g = uc[56 + tid];
        float2 A00 = {g[0], g[1]}, A01 = {g[2], g[3]};
        float2 A10 = {g[4], g[5]}, A11 = {g[6], g[7]};
        float M00 = A00.x*A00.x + A00.y*A00.y - (A10.x*A10.x + A10.y*A10.y);
        float M11 = A01.x*A01.x + A01.y*A01.y - (A11.x*A11.x + A11.y*A11.y);
        float2 M01 = csub(cmulc(A00, A01), cmulc(A10, A11));   // = b - i c
        abcd[tid][0] = 0.5f * (M00 + M11);
        abcd[tid][1] = M01.x;
        abcd[tid][2] = -M01.y;
        abcd[tid][3] = 0.5f * (M00 - M11);
    }

    // ---- site tensors At (verified r19) ----
    for (int idx = tid; idx < 14 * 2 * 64; idx += 1024) {
        const int s = idx >> 7, h = (idx >> 6) & 1, ent = idx & 63;
        const int i = ent >> 3, j = ent & 7;
        const int j2p = i >> 2, jp = (i >> 1) & 1, cb = i & 1;
        const int j2  = j >> 2, jv = (j >> 1) & 1, cp = j & 1;
        const int q = 13 - s;
        const float* u3 = uc[42 + q];
        const float* V2 = uc[28 + q];
        const float* V1 = uc[14 + q];
        const float* ph = uc[q];
        float2 f1 = {u3[h*4 + cp*2],           u3[h*4 + cp*2 + 1]};
        float2 f2 = {V2[(cp^cb)*4 + j2*2],     V2[(cp^cb)*4 + j2*2 + 1]};
        float2 f3 = {V1[(j2^j2p)*4 + jv*2],    V1[(j2^j2p)*4 + jv*2 + 1]};
        float2 f4 = {ph[(jv^jp)*4],            ph[(jv^jp)*4 + 1]};
        At[s][h][ent] = cmul(cmul(f1, f2), cmul(f3, f4));
    }
    if (tid < 64) {
        LI[14][tid] = make_float2(tid == 0 ? 1.0f : 0.0f, 0.0f);
        LZ[14][tid] = LI[14][tid];
        Ps[0][tid]  = make_float2(1.0f, 0.0f);
    }
    __syncthreads();

    // ---- merged sweeps in ONE wave: L^I, L^Z (site 13-t), P (site t) ----
    if (wave == 0) {
        float2 L_I = make_float2(lane == 0 ? 1.0f : 0.0f, 0.0f);
        float2 L_Z = L_I;
        float2 P   = make_float2(1.0f, 0.0f);
        #pragma unroll
        for (int t = 0; t < 14; ++t) {
            const int sL = 13 - t;
            const int sP = t;
            float2 BI0 = {0,0}, BI1 = {0,0};
            float2 BZ0 = {0,0}, BZ1 = {0,0};
            float2 D0  = {0,0}, D1  = {0,0};
            #pragma unroll
            for (int l = 0; l < 8; ++l) {
                float2 LIl = shfl2(L_I, i8*8 + l);
                float2 LZl = shfl2(L_Z, i8*8 + l);
                float2 Pl  = shfl2(P,   i8*8 + l);
                float2 A0 = At[sL][0][l*8 + j8], A1 = At[sL][1][l*8 + j8];
                BI0 = cadd(BI0, cmul(LIl, A0)); BI1 = cadd(BI1, cmul(LIl, A1));
                BZ0 = cadd(BZ0, cmul(LZl, A0)); BZ1 = cadd(BZ1, cmul(LZl, A1));
                D0 = cadd(D0, cmul(Pl, At[sP][0][j8*8 + l]));
                D1 = cadd(D1, cmul(Pl, At[sP][1][j8*8 + l]));
            }
            float2 aI = {0,0}, aZ = {0,0}, aP = {0,0};
            #pragma unroll
            for (int k = 0; k < 8; ++k) {
                float2 A0c = At[sL][0][k*8 + i8], A1c = At[sL][1][k*8 + i8];
                float2 BI0k = shfl2(BI0, k*8 + j8), BI1k = shfl2(BI1, k*8 + j8);
                float2 BZ0k = shfl2(BZ0, k*8 + j8), BZ1k = shfl2(BZ1, k*8 + j8);
                aI = cadd(aI, cadd(cmulc(A0c, BI0k), cmulc(A1c, BI1k)));
                aZ = cadd(aZ, csub(cmulc(A0c, BZ0k), cmulc(A1c, BZ1k)));
                aP = cadd(aP, cmulc(At[sP][0][i8*8 + k], shfl2(D0, k*8 + j8)));
                aP = cadd(aP, cmulc(At[sP][1][i8*8 + k], shfl2(D1, k*8 + j8)));
            }
            L_I = aI; L_Z = aZ; P = aP;
            LI[sL][lane] = L_I;
            LZ[sL][lane] = L_Z;
            if (sP + 1 < 14) Ps[sP + 1][lane] = P;
        }
    }
    __syncthreads();

    // ---- 42 center tasks (q, term): term 0=Tz, 1=Tx, 2=Ty (verified r20) ----
    for (int round = 0; round < 3; ++round) {
        const int tk = wave + 16 * round;
        if (tk < 42) {
            const int q = tk / 3, term = tk % 3, b = 13 - q;
            float2 Lr = (term == 1) ? LI[b+1][lane] : LZ[b+1][lane];
            float2 B0 = {0,0}, B1 = {0,0};
            #pragma unroll
            for (int l = 0; l < 8; ++l) {
                float2 Ll = shfl2(Lr, i8*8 + l);
                if (term == 0) {
                    B0 = cadd(B0, cmul(Ll, At[b][0][l*8 + j8]));
                    B1 = cadd(B1, cmul(Ll, At[b][1][l*8 + j8]));
                } else {
                    B0 = cadd(B0, cmul(Ll, At[b][1][l*8 + j8]));
                    B1 = cadd(B1, cmul(Ll, At[b][0][l*8 + j8]));
                }
            }
            float2 cm;
            if (term == 0) {
                float2 acc = {0,0};
                #pragma unroll
                for (int k = 0; k < 8; ++k) {
                    acc = cadd(acc, cmulc(At[b][0][k*8 + i8], shfl2(B0, k*8 + j8)));
                    acc = csub(acc, cmulc(At[b][1][k*8 + i8], shfl2(B1, k*8 + j8)));
                }
                cm = acc;
            } else if (term == 1) {
                float2 acc = {0,0};
                #pragma unroll
                for (int k = 0; k < 8; ++k) {
                    acc = cadd(acc, cmulc(At[b][0][k*8 + i8], shfl2(B0, k*8 + j8)));
                    acc = cadd(acc, cmulc(At[b][1][k*8 + i8], shfl2(B1, k*8 + j8)));
                }
                cm = acc;
            } else {
                float2 a0 = {0,0}, a1 = {0,0};
                #pragma unroll
                for (int k = 0; k < 8; ++k) {
                    a0 = cadd(a0, cmulc(At[b][0][k*8 + i8], shfl2(B0, k*8 + j8)));
                    a1 = cadd(a1, cmulc(At[b][1][k*8 + i8], shfl2(B1, k*8 + j8)));
                }
                float2 d = csub(a1, a0);            // i*(a1-a0)
                cm = make_float2(-d.y, d.x);
            }
            if (term >= 1 && b >= 1) {
                float2 C0 = {0,0}, C1 = {0,0};
                #pragma unroll
                for (int l = 0; l < 8; ++l) {
                    float2 Ll = shfl2(cm, i8*8 + l);
                    C0 = cadd(C0, cmul(Ll, At[b-1][1][l*8 + j8]));
                    C1 = cadd(C1, cmul(Ll, At[b-1][0][l*8 + j8]));
                }
                float2 acc = {0,0};
                #pragma unroll
                for (int k = 0; k < 8; ++k) {
                    acc = cadd(acc, cmulc(At[b-1][0][k*8 + i8], shfl2(C0, k*8 + j8)));
                    acc = cadd(acc, cmulc(At[b-1][1][k*8 + i8], shfl2(C1, k*8 + j8)));
                }
                cm = acc;
            }
            const float2* P = (term == 0) ? Ps[b] : Ps[(b >= 1) ? (b - 1) : 0];
            float v = cm.x * P[lane].x - cm.y * P[lane].y;
            #pragma unroll
            for (int off = 32; off > 0; off >>= 1) v += __shfl_down(v, off, 64);
            if (lane == 0) Tv2[q][term] = v;
        }
    }
    __syncthreads();

    if (tid < NQ)
        Eq[tid] = abcd[tid][0] + abcd[tid][1] * Tv2[tid][1]
                + abcd[tid][2] * Tv2[tid][2] + abcd[tid][3] * Tv2[tid][0];
    __syncthreads();

    // ---- head ----
    if (tid < NCLS) {
        float acc = bias[tid];
        #pragma unroll
        for (int qq = 0; qq < NQ; ++qq) acc += Wm[tid * NQ + qq] * Eq[qq];
        out[e * NCLS + tid] = acc;
    }
}

extern "C" void kernel_launch(void* const* d_in, const int* in_sizes, int n_in,
                              void* d_out, int out_size, void* d_ws, size_t ws_size,
                              hipStream_t stream)
{
    const float* x    = (const float*)d_in[0];   // (64, 196)
    const float* W    = (const float*)d_in[1];   // (10, 14)
    const float* bias = (const float*)d_in[2];   // (10,)
    float*       out  = (float*)d_out;           // (64, 10)
    (void)d_ws; (void)ws_size;                   // no workspace needed

    hipLaunchKernelGGL(qvc_mps, dim3(64), dim3(1024), 0, stream, x, W, bias, out);
}

// Round 22
// 34.960 us; speedup vs baseline: 1.3819x; 1.3819x over previous
//
#include <hip/hip_runtime.h>

#define NQ    14
#define NPAR  196
#define NCLS  10

// ============================================================================
// MPS/Heisenberg formulation — algebra verified on HW in r19/r20 (absmax 0).
// r22 = r20 verbatim (best measured: 34.8 us). r21's merged-chain + full
// unroll regressed (48.3): single-wave LDS-pipe concentration + I-cache bloat.
//   - each wave's 64 lanes hold one 8x8 complex matrix (lane = i*8+j)
//   - matmul stages use __shfl gathers + read-only LDS At -> NO __syncthreads
//   - 3 transfer sweeps = independent single-wave register chains (waves 0-2)
//   - 42 center tasks (14 q x 3 terms) fully parallel across 16 waves
// psi2 = chi=4 TT (r14/r16-verified); U3 absorbed into chi=8 site tensors At;
// Heisenberg tail: O_q = a I + b X_b X_{b-1} + c (Z..Z) Y_b X_{b-1} + d (Z..Z) Z_b.
// ============================================================================

__device__ __forceinline__ float2 cmul(float2 a, float2 b) {
    return make_float2(a.x*b.x - a.y*b.y, a.x*b.y + a.y*b.x);
}
__device__ __forceinline__ float2 cmulc(float2 a, float2 b) {   // conj(a)*b
    return make_float2(a.x*b.x + a.y*b.y, a.x*b.y - a.y*b.x);
}
__device__ __forceinline__ float2 cadd(float2 a, float2 b) {
    return make_float2(a.x + b.x, a.y + b.y);
}
__device__ __forceinline__ float2 csub(float2 a, float2 b) {
    return make_float2(a.x - b.x, a.y - b.y);
}
__device__ __forceinline__ float2 shfl2(float2 v, int src) {
    return make_float2(__shfl(v.x, src, 64), __shfl(v.y, src, 64));
}

__global__ void __launch_bounds__(1024)
qvc_mps(const float* __restrict__ x, const float* __restrict__ Wm,
        const float* __restrict__ bias, float* __restrict__ out)
{
    __shared__ float  uc[70][8];
    __shared__ float2 At[14][2][64];   // site s, phys h, 8x8 [row*8+col]
    __shared__ float2 LI[15][64];      // L^I prefixes (LI[14] = base)
    __shared__ float2 LZ[15][64];      // L^Z prefixes
    __shared__ float2 Ps[14][64];      // Ps[t] = P after sites 0..t-1 (Ps[0]=ones)
    __shared__ float  abcd[NQ][4];
    __shared__ float  Tv2[NQ][3];      // Tz, Tx, Ty per q
    __shared__ float  Eq[NQ];

    const int e = blockIdx.x;
    const int tid = threadIdx.x;
    const int wave = tid >> 6, lane = tid & 63;
    const int i8 = lane >> 3, j8 = lane & 7;
    const float* xb = x + e * NPAR;

    // ---- all 70 gate 2x2s (verified) ----
    if (tid < 70) {
        const int layer = tid / 14, q = tid % 14;
        const int pidx = (layer < 4) ? layer * 42 + q * 3 : 168 + q * 2;
        float a1 = 0.5f * xb[pidx], a2 = 0.5f * xb[pidx + 1];
        float s1, c1, s2, c2;
        sincosf(a1, &s1, &c1);
        sincosf(a2, &s2, &c2);
        float A00r =  c2 * c1, A00i =  s2 * s1;
        float A01r = -s2 * c1, A01i = -c2 * s1;
        float A10r =  s2 * c1, A10i = -c2 * s1;
        float A11r =  c2 * c1, A11i = -s2 * s1;
        float U0, U1, U2, U3, U4, U5, U6, U7;
        if (layer < 4) {
            float a3 = 0.5f * xb[pidx + 2]; float s3, c3; sincosf(a3, &s3, &c3);
            U0 = c3 * A00r + s3 * A00i; U1 = c3 * A00i - s3 * A00r;
            U2 = c3 * A01r + s3 * A01i; U3 = c3 * A01i - s3 * A01r;
            U4 = c3 * A10r - s3 * A10i; U5 = c3 * A10i + s3 * A10r;
            U6 = c3 * A11r - s3 * A11i; U7 = c3 * A11i + s3 * A11r;
        } else {
            U0 = A00r; U1 = A00i; U2 = A01r; U3 = A01i;
            U4 = A10r; U5 = A10i; U6 = A11r; U7 = A11i;
        }
        uc[tid][0] = U0; uc[tid][1] = U1; uc[tid][2] = U2; uc[tid][3] = U3;
        uc[tid][4] = U4; uc[tid][5] = U5; uc[tid][6] = U6; uc[tid][7] = U7;
    }
    __syncthreads();

    // ---- Pauli coefficients of M_q = u4^dag Z u4 (verified r19) ----
    if (tid < NQ) {
        const float* g = uc[56 + tid];
        float2 A00 = {g[0], g[1]}, A01 = {g[2], g[3]};
        float2 A10 = {g[4], g[5]}, A11 = {g[6], g[7]};
        float M00 = A00.x*A00.x + A00.y*A00.y - (A10.x*A10.x + A10.y*A10.y);
        float M11 = A01.x*A01.x + A01.y*A01.y - (A11.x*A11.x + A11.y*A11.y);
        float2 M01 = csub(cmulc(A00, A01), cmulc(A10, A11));   // = b - i c
        abcd[tid][0] = 0.5f * (M00 + M11);
        abcd[tid][1] = M01.x;
        abcd[tid][2] = -M01.y;
        abcd[tid][3] = 0.5f * (M00 - M11);
    }

    // ---- site tensors At (verified r19) ----
    for (int idx = tid; idx < 14 * 2 * 64; idx += 1024) {
        const int s = idx >> 7, h = (idx >> 6) & 1, ent = idx & 63;
        const int i = ent >> 3, j = ent & 7;
        const int j2p = i >> 2, jp = (i >> 1) & 1, cb = i & 1;
        const int j2  = j >> 2, jv = (j >> 1) & 1, cp = j & 1;
        const int q = 13 - s;
        const float* u3 = uc[42 + q];
        const float* V2 = uc[28 + q];
        const float* V1 = uc[14 + q];
        const float* ph = uc[q];
        float2 f1 = {u3[h*4 + cp*2],           u3[h*4 + cp*2 + 1]};
        float2 f2 = {V2[(cp^cb)*4 + j2*2],     V2[(cp^cb)*4 + j2*2 + 1]};
        float2 f3 = {V1[(j2^j2p)*4 + jv*2],    V1[(j2^j2p)*4 + jv*2 + 1]};
        float2 f4 = {ph[(jv^jp)*4],            ph[(jv^jp)*4 + 1]};
        At[s][h][ent] = cmul(cmul(f1, f2), cmul(f3, f4));
    }
    if (tid < 64) {
        LI[14][tid] = make_float2(tid == 0 ? 1.0f : 0.0f, 0.0f);
        LZ[14][tid] = LI[14][tid];
        Ps[0][tid]  = make_float2(1.0f, 0.0f);
    }
    __syncthreads();

    // ---- sweeps: wave0 = L^I, wave1 = L^Z (top-down), wave2 = P (bottom-up).
    // Barrier-free: in-wave shuffles; prefixes stored for the center phase.
    if (wave == 0 || wave == 1) {
        float2 L = make_float2(lane == 0 ? 1.0f : 0.0f, 0.0f);
        for (int t = 0; t < 14; ++t) {
            const int s = 13 - t;
            float2 B0 = {0,0}, B1 = {0,0};
            #pragma unroll
            for (int l = 0; l < 8; ++l) {
                float2 Ll = shfl2(L, i8*8 + l);
                B0 = cadd(B0, cmul(Ll, At[s][0][l*8 + j8]));
                B1 = cadd(B1, cmul(Ll, At[s][1][l*8 + j8]));
            }
            float2 acc = {0,0};
            #pragma unroll
            for (int k = 0; k < 8; ++k) {
                float2 t0 = cmulc(At[s][0][k*8 + i8], shfl2(B0, k*8 + j8));
                float2 t1 = cmulc(At[s][1][k*8 + i8], shfl2(B1, k*8 + j8));
                acc = cadd(acc, (wave == 0) ? cadd(t0, t1) : csub(t0, t1));
            }
            L = acc;
            ((wave == 0) ? LI[s] : LZ[s])[lane] = L;
        }
    } else if (wave == 2) {
        float2 P = make_float2(1.0f, 0.0f);
        for (int s = 0; s < 14; ++s) {
            float2 D0 = {0,0}, D1 = {0,0};
            #pragma unroll
            for (int l = 0; l < 8; ++l) {
                float2 Pl = shfl2(P, i8*8 + l);
                D0 = cadd(D0, cmul(Pl, At[s][0][j8*8 + l]));
                D1 = cadd(D1, cmul(Pl, At[s][1][j8*8 + l]));
            }
            float2 acc = {0,0};
            #pragma unroll
            for (int k = 0; k < 8; ++k) {
                acc = cadd(acc, cmulc(At[s][0][i8*8 + k], shfl2(D0, k*8 + j8)));
                acc = cadd(acc, cmulc(At[s][1][i8*8 + k], shfl2(D1, k*8 + j8)));
            }
            P = acc;
            if (s + 1 < 14) Ps[s + 1][lane] = P;
        }
    }
    __syncthreads();

    // ---- 42 center tasks (q, term): term 0=Tz, 1=Tx, 2=Ty; all in parallel ----
    for (int round = 0; round < 3; ++round) {
        const int tk = wave + 16 * round;
        if (tk < 42) {
            const int q = tk / 3, term = tk % 3, b = 13 - q;
            float2 Lr = (term == 1) ? LI[b+1][lane] : LZ[b+1][lane];
            // stage at site b (Z: same-h; X/Y: swapped-h ket side)
            float2 B0 = {0,0}, B1 = {0,0};
            #pragma unroll
            for (int l = 0; l < 8; ++l) {
                float2 Ll = shfl2(Lr, i8*8 + l);
                if (term == 0) {
                    B0 = cadd(B0, cmul(Ll, At[b][0][l*8 + j8]));
                    B1 = cadd(B1, cmul(Ll, At[b][1][l*8 + j8]));
                } else {
                    B0 = cadd(B0, cmul(Ll, At[b][1][l*8 + j8]));
                    B1 = cadd(B1, cmul(Ll, At[b][0][l*8 + j8]));
                }
            }
            float2 cm;
            if (term == 0) {
                float2 acc = {0,0};
                #pragma unroll
                for (int k = 0; k < 8; ++k) {
                    acc = cadd(acc, cmulc(At[b][0][k*8 + i8], shfl2(B0, k*8 + j8)));
                    acc = csub(acc, cmulc(At[b][1][k*8 + i8], shfl2(B1, k*8 + j8)));
                }
                cm = acc;
            } else if (term == 1) {
                float2 acc = {0,0};
                #pragma unroll
                for (int k = 0; k < 8; ++k) {
                    acc = cadd(acc, cmulc(At[b][0][k*8 + i8], shfl2(B0, k*8 + j8)));
                    acc = cadd(acc, cmulc(At[b][1][k*8 + i8], shfl2(B1, k*8 + j8)));
                }
                cm = acc;
            } else {
                float2 a0 = {0,0}, a1 = {0,0};
                #pragma unroll
                for (int k = 0; k < 8; ++k) {
                    a0 = cadd(a0, cmulc(At[b][0][k*8 + i8], shfl2(B0, k*8 + j8)));
                    a1 = cadd(a1, cmulc(At[b][1][k*8 + i8], shfl2(B1, k*8 + j8)));
                }
                float2 d = csub(a1, a0);            // i*(a1-a0)
                cm = make_float2(-d.y, d.x);
            }
            // X-step at site b-1 for Tx, Ty
            if (term >= 1 && b >= 1) {
                float2 C0 = {0,0}, C1 = {0,0};
                #pragma unroll
                for (int l = 0; l < 8; ++l) {
                    float2 Ll = shfl2(cm, i8*8 + l);
                    C0 = cadd(C0, cmul(Ll, At[b-1][1][l*8 + j8]));
                    C1 = cadd(C1, cmul(Ll, At[b-1][0][l*8 + j8]));
                }
                float2 acc = {0,0};
                #pragma unroll
                for (int k = 0; k < 8; ++k) {
                    acc = cadd(acc, cmulc(At[b-1][0][k*8 + i8], shfl2(C0, k*8 + j8)));
                    acc = cadd(acc, cmulc(At[b-1][1][k*8 + i8], shfl2(C1, k*8 + j8)));
                }
                cm = acc;
            }
            // contract with suffix; real part; in-wave reduce
            const float2* P = (term == 0) ? Ps[b] : Ps[(b >= 1) ? (b - 1) : 0];
            float v = cm.x * P[lane].x - cm.y * P[lane].y;
            #pragma unroll
            for (int off = 32; off > 0; off >>= 1) v += __shfl_down(v, off, 64);
            if (lane == 0) Tv2[q][term] = v;
        }
    }
    __syncthreads();

    if (tid < NQ)
        Eq[tid] = abcd[tid][0] + abcd[tid][1] * Tv2[tid][1]
                + abcd[tid][2] * Tv2[tid][2] + abcd[tid][3] * Tv2[tid][0];
    __syncthreads();

    // ---- head ----
    if (tid < NCLS) {
        float acc = bias[tid];
        #pragma unroll
        for (int qq = 0; qq < NQ; ++qq) acc += Wm[tid * NQ + qq] * Eq[qq];
        out[e * NCLS + tid] = acc;
    }
}

extern "C" void kernel_launch(void* const* d_in, const int* in_sizes, int n_in,
                              void* d_out, int out_size, void* d_ws, size_t ws_size,
                              hipStream_t stream)
{
    const float* x    = (const float*)d_in[0];   // (64, 196)
    const float* W    = (const float*)d_in[1];   // (10, 14)
    const float* bias = (const float*)d_in[2];   // (10,)
    float*       out  = (float*)d_out;           // (64, 10)
    (void)d_ws; (void)ws_size;                   // no workspace needed

    hipLaunchKernelGGL(qvc_mps, dim3(64), dim3(1024), 0, stream, x, W, bias, out);
}